// Round 6
// baseline (308.147 us; speedup 1.0000x reference)
//
#include <hip/hip_runtime.h>
#include <hip/hip_bf16.h>
#include <math.h>

// Problem dims
#define NB 256
#define NT 512
#define NF 128
#define NCOH 64         // coh_pts
#define NIN 192         // F + coh_pts
#define NBS 384         // 3*bulk_pts
#define NROWS (NB*NT)   // 131072

// Material constants (match fp64->fp32 of reference)
#define C11 1098.9010989010989f
#define C12 329.67032967032966f
#define C33 384.61538461538464f
#define H3G 1253.8461538461538f   // 3*G + HARD
#define HOVER 0.07975460122699386f // HARD / (3*G + HARD)

typedef __attribute__((ext_vector_type(8))) short bf16x8;   // 8 bf16 = 4 VGPR
typedef __attribute__((ext_vector_type(4))) float f32x4;    // MFMA acc
typedef __attribute__((ext_vector_type(8))) unsigned short ushort8v;
typedef __attribute__((ext_vector_type(4))) unsigned short ushort4v;

// s_waitcnt with only vmcnt constrained (expcnt=7, lgkmcnt=15 = no-wait)
#define WAITCNT_VM(N) __builtin_amdgcn_s_waitcnt(0x0F70 | ((N) & 15) | (((N) >> 4) << 14))

// A operand (x | dmg), bf16. TILED layout: [kchunk 0..5][row 0..NROWS)[32]
// so one 16-row fragment = 1 KB contiguous (wave-coalesced global load).
#define PS ((size_t)NROWS * 32)     // plane stride in ushorts
__device__ unsigned short g_Ahi[6 * PS];
// B (D-folded W12, hi+lo split) in FRAGMENT-MAJOR order:
// [nblk 0..5][kc 0..5][part 0..1][nf 0..3][lane 0..63][8]
__device__ unsigned short g_Bres[2 * NBS * NIN];
// W11 fragment-major hi/lo: [kc 0..3][part 0..1][nf 0..7][lane 0..63][8] = 64 KB
__device__ unsigned short g_W11res[32768];

static __device__ __forceinline__ unsigned short f2bf(float v) {
    __hip_bfloat16 h = __float2bfloat16(v);
    return *reinterpret_cast<unsigned short*>(&h);
}
static __device__ __forceinline__ float bf2f(unsigned short u) {
    unsigned int x = ((unsigned int)u) << 16;
    return *reinterpret_cast<float*>(&x);
}
static __device__ __forceinline__ void async_copy16(const void* g, void* l) {
    __builtin_amdgcn_global_load_lds(
        (const __attribute__((address_space(1))) unsigned int*)g,
        (__attribute__((address_space(3))) unsigned int*)l, 16, 0, 0);
}

// ---------------------------------------------------------------------------
// K0: fold plane-stress D into W12, split bf16 hi/lo, emit fragment-major.
// ---------------------------------------------------------------------------
__global__ __launch_bounds__(256) void k0_w12(const float* __restrict__ W12)
{
    const int idx = blockIdx.x * 256 + threadIdx.x;   // < 294912
    const int e    = idx & 7;
    const int l    = (idx >> 3) & 63;
    const int nf   = (idx >> 9) & 3;
    const int part = (idx >> 11) & 1;
    const int kc   = (idx >> 12) % 6;
    const int nblk = idx / 24576;                     // 6*4096
    const int n = nblk * 64 + nf * 16 + (l & 15);
    const int k = kc * 32 + (l >> 4) * 8 + e;
    const int p = n / 3, j = n - 3 * p;
    const float* w = W12 + (size_t)(3 * p) * NIN;
    float v;
    if (j == 0)      v = C11 * w[k]           + C12 * w[NIN + k];
    else if (j == 1) v = C12 * w[k]           + C11 * w[NIN + k];
    else             v = C33 * w[2 * NIN + k];
    unsigned short h = f2bf(v);
    g_Bres[idx] = part ? f2bf(v - bf2f(h)) : h;
}

// ---------------------------------------------------------------------------
// K0b: W11 -> fragment-major bf16 hi/lo (for k1's MFMA).
// ---------------------------------------------------------------------------
__global__ __launch_bounds__(256) void k0b_w11(const float* __restrict__ W11)
{
    const int idx = blockIdx.x * 256 + threadIdx.x;   // < 32768
    const int e    = idx & 7;
    const int l    = (idx >> 3) & 63;
    const int nf   = (idx >> 9) & 7;
    const int part = (idx >> 12) & 1;
    const int kc   = idx >> 13;                       // 0..3
    const int n = nf * 16 + (l & 15);
    const int k = kc * 32 + (l >> 4) * 8 + e;
    const float v = W11[(size_t)n * NF + k];
    unsigned short h = f2bf(v);
    g_W11res[idx] = part ? f2bf(v - bf2f(h)) : h;
}

// ---------------------------------------------------------------------------
// K1 (fused kx+fc11): reads x fp32 directly in fragment order, converts
// hi/lo bf16 in-register, stores hi planes 0..3 for k3, runs the W11 MFMA.
// C = Wh*xh + Wl*xh + Wh*xl. dnew computed in-register, stored bf16 c-major.
// ---------------------------------------------------------------------------
__global__ __launch_bounds__(256) void k1_fc11(
    const float* __restrict__ x, const float* __restrict__ b11,
    unsigned short* __restrict__ dnT)
{
    __shared__ unsigned short Ws[32768];   // 64 KB

    const int tid = threadIdx.x;
    const int lane = tid & 63, w = tid >> 6;
    const int fr = lane & 15, fq = lane >> 4;
    const int xbase = blockIdx.x * 128 + w * 32;

    // stage W11res (64 KB linear copy)
#pragma unroll
    for (int i = 0; i < 16; ++i)
        async_copy16((const char*)g_W11res + tid * 16 + i * 4096,
                     (char*)Ws + tid * 16 + i * 4096);

    f32x4 acc[8][2];
#pragma unroll
    for (int q = 0; q < 8; ++q)
#pragma unroll
        for (int f = 0; f < 2; ++f) acc[q][f] = (f32x4){0.f, 0.f, 0.f, 0.f};

    WAITCNT_VM(0);
    __builtin_amdgcn_s_barrier();

#pragma unroll
    for (int kc = 0; kc < 4; ++kc) {
        bf16x8 ah[2], al[2];
#pragma unroll
        for (int f = 0; f < 2; ++f) {
            const int row = xbase + f * 16 + fr;
            const float* xs = x + (size_t)row * NF + kc * 32 + fq * 8;
            float4 v0 = ((const float4*)xs)[0];
            float4 v1 = ((const float4*)xs)[1];
            float v[8] = {v0.x, v0.y, v0.z, v0.w, v1.x, v1.y, v1.z, v1.w};
            ushort8v h, lo;
#pragma unroll
            for (int i = 0; i < 8; ++i) {
                h[i]  = f2bf(v[i]);
                lo[i] = f2bf(v[i] - bf2f(h[i]));
            }
            *(ushort8v*)(g_Ahi + (size_t)kc * PS + (size_t)row * 32 + fq * 8) = h;
            ah[f] = *reinterpret_cast<bf16x8*>(&h);
            al[f] = *reinterpret_cast<bf16x8*>(&lo);
        }
#pragma unroll
        for (int q = 0; q < 8; ++q) {
            bf16x8 wh = *(const bf16x8*)&Ws[(kc * 16 + q) * 512 + lane * 8];
            bf16x8 wl = *(const bf16x8*)&Ws[(kc * 16 + 8 + q) * 512 + lane * 8];
#pragma unroll
            for (int f = 0; f < 2; ++f) {
                acc[q][f] = __builtin_amdgcn_mfma_f32_16x16x32_bf16(
                    wh, ah[f], acc[q][f], 0, 0, 0);
                acc[q][f] = __builtin_amdgcn_mfma_f32_16x16x32_bf16(
                    wl, ah[f], acc[q][f], 0, 0, 0);
                acc[q][f] = __builtin_amdgcn_mfma_f32_16x16x32_bf16(
                    wh, al[f], acc[q][f], 0, 0, 0);
            }
        }
    }

#pragma unroll
    for (int q = 0; q < 8; ++q) {
        float4 bv = *(const float4*)(b11 + q * 16 + fq * 4);
#pragma unroll
        for (int f = 0; f < 2; ++f) {
            const int xrow = xbase + f * 16 + fr;
            float z[4] = {acc[q][f][0] + bv.x, acc[q][f][1] + bv.y,
                          acc[q][f][2] + bv.z, acc[q][f][3] + bv.w};
#pragma unroll
            for (int pr = 0; pr < 2; ++pr) {
                float jn = fmaxf(z[2 * pr], 0.0f);
                float zs = z[2 * pr + 1];
                float js = (zs > 0.0f) ? zs : 0.01f * zs;
                float delta = sqrtf(jn * jn + js * js + 1e-12f);
                float dn = 0.1f * (delta - 0.01f) / (fmaxf(delta, 1e-12f) * 0.09f);
                dn = fminf(fmaxf(dn, 0.0f), 1.0f);
                dnT[(size_t)(q * 8 + fq * 2 + pr) * NROWS + xrow] = f2bf(dn);
            }
        }
    }
}

// ---------------------------------------------------------------------------
// K2 (two-phase parallel cummax on c-major bf16 dnT).
// ---------------------------------------------------------------------------
__global__ __launch_bounds__(64) void k2a(const unsigned short* __restrict__ dnT,
                                          float* __restrict__ totals)
{
    const int b = blockIdx.x >> 3, seg = blockIdx.x & 7;
    const int c = threadIdx.x;
    const ushort8v* p = (const ushort8v*)(dnT + (size_t)c * NROWS + b * NT + seg * 64);
    float m = 0.0f;
#pragma unroll
    for (int g = 0; g < 8; ++g) {
        ushort8v v = p[g];
#pragma unroll
        for (int i = 0; i < 8; ++i) m = fmaxf(m, bf2f(v[i]));
    }
    totals[(size_t)(b * 8 + seg) * 64 + c] = m;
}

__global__ __launch_bounds__(64) void k2b(const unsigned short* __restrict__ dnT,
                                          const float* __restrict__ totals)
{
    const int b = blockIdx.x >> 3, seg = blockIdx.x & 7;
    const int c = threadIdx.x;
    float carry = 0.0f;
    for (int s = 0; s < seg; ++s)
        carry = fmaxf(carry, totals[(size_t)(b * 8 + s) * 64 + c]);
    const ushort8v* p = (const ushort8v*)(dnT + (size_t)c * NROWS + b * NT + seg * 64);
    unsigned short* ah = g_Ahi + (size_t)(4 + (c >> 5)) * PS
                       + (size_t)(b * NT + seg * 64) * 32 + (c & 31);
    float m = carry;
#pragma unroll
    for (int g = 0; g < 8; ++g) {
        ushort8v v = p[g];
#pragma unroll
        for (int i = 0; i < 8; ++i) {
            m = fmaxf(m, bf2f(v[i]));
            ah[(size_t)(g * 8 + i) * 32] = f2bf(m);
        }
    }
}

// ---------------------------------------------------------------------------
// K3: sig_tr = A @ B^T via MFMA, C = Ahi*(Bhi + Blo). B LDS-resident
// fragment-major (48 KB, zero conflicts, no loop barriers); A from global,
// double-buffered. XCD swizzle: 6 n-blocks of one m-tile share an XCD.
// NEW epilogue: acc -> LDS transpose tile (reusing Bs) -> fully-coalesced
// global stores (each wave-store = two contiguous 512 B runs).
// ---------------------------------------------------------------------------
__global__ __launch_bounds__(256, 3) void k3_mfma(unsigned short* __restrict__ sigT)
{
    __shared__ unsigned short Bs[24576];   // 48 KB: [kc][part][nf][lane][8]

    const int tid = threadIdx.x;
    const int lane = tid & 63, w = tid >> 6;
    const int id = blockIdx.x;
    const int sw = (id & 7) * 384 + (id >> 3);
    const int nblk = sw % 6;
    const int m0 = (sw / 6) * 256;
    const int n0 = nblk * 64;
    const int wm = w * 64;
    const int fr = lane & 15, fq = lane >> 4;

    const size_t abase = (size_t)(m0 + wm + fr) * 32 + fq * 8;

    bf16x8 a0[4], a1[4];
#pragma unroll
    for (int mi = 0; mi < 4; ++mi)
        a0[mi] = *(const bf16x8*)(g_Ahi + abase + mi * 512);

    {
        const char* bsrc = (const char*)g_Bres + (size_t)nblk * 49152;
#pragma unroll
        for (int i = 0; i < 12; ++i)
            async_copy16(bsrc + tid * 16 + i * 4096, (char*)Bs + tid * 16 + i * 4096);
    }
    WAITCNT_VM(0);
    __builtin_amdgcn_s_barrier();

    f32x4 acc[4][4];
#pragma unroll
    for (int mi = 0; mi < 4; ++mi)
#pragma unroll
        for (int ni = 0; ni < 4; ++ni) acc[mi][ni] = (f32x4){0.f, 0.f, 0.f, 0.f};

#pragma unroll
    for (int c = 0; c < 6; ++c) {
        bf16x8* acur = (c & 1) ? a1 : a0;
        bf16x8* anxt = (c & 1) ? a0 : a1;
        if (c < 5) {
#pragma unroll
            for (int mi = 0; mi < 4; ++mi)
                anxt[mi] = *(const bf16x8*)(g_Ahi + (size_t)(c + 1) * PS
                                            + abase + mi * 512);
        }
        bf16x8 bh[4], bl[4];
#pragma unroll
        for (int ni = 0; ni < 4; ++ni) {
            bh[ni] = *(const bf16x8*)&Bs[((c * 8 + ni) << 9) + lane * 8];
            bl[ni] = *(const bf16x8*)&Bs[((c * 8 + 4 + ni) << 9) + lane * 8];
        }
#pragma unroll
        for (int mi = 0; mi < 4; ++mi)
#pragma unroll
            for (int ni = 0; ni < 4; ++ni) {
                acc[mi][ni] = __builtin_amdgcn_mfma_f32_16x16x32_bf16(
                    acur[mi], bh[ni], acc[mi][ni], 0, 0, 0);
                acc[mi][ni] = __builtin_amdgcn_mfma_f32_16x16x32_bf16(
                    acur[mi], bl[ni], acc[mi][ni], 0, 0, 0);
            }
    }

    // ---- epilogue: LDS transpose (reuse Bs) then coalesced stores ----
    __syncthreads();                       // all waves done reading Bs
    unsigned short* T = Bs;                // [64 cols][272] (row 544 B, 16B-aligned)
#pragma unroll
    for (int mi = 0; mi < 4; ++mi)
#pragma unroll
        for (int ni = 0; ni < 4; ++ni) {
            const int cIdx = ni * 16 + fr;
            const int tloc = wm + mi * 16 + fq * 4;
            ushort4v h;
#pragma unroll
            for (int r = 0; r < 4; ++r) h[r] = f2bf(acc[mi][ni][r]);
            *(ushort4v*)&T[cIdx * 272 + tloc] = h;
        }
    __syncthreads();

    const int b_idx = m0 >> 9;
    const int tq = lane & 31, c2 = lane >> 5;
    const size_t colbase = (((size_t)(b_idx * NBS + n0)) << 9) + (m0 & 511);
#pragma unroll
    for (int it = 0; it < 8; ++it) {
        const int cc = w * 16 + it * 2 + c2;
        ushort8v v = *(const ushort8v*)&T[cc * 272 + tq * 8];
        *(ushort8v*)(sigT + colbase + ((size_t)cc << 9) + tq * 8) = v;
    }
}

// ---------------------------------------------------------------------------
// K45 (fused scan + output): one block per b, 512 threads, 128 KB LDS.
// Phase 1 (threads 0..127): yield-stress scan u' = u + HOVER*max(seq-u,0)
// per chain p, u written bf16 into LDS (16B-chunk XOR swizzle so phase-2
// row reads are ~4-way, not 64-way). No uT global traffic.
// Phase 2 (all 512): thread t; recompute seq from sigT (warm in L2/L3),
// scale = min(1, u/seq), GEMM 384->6 (W2 via lane-uniform scalar loads),
// softplus, store.
// ---------------------------------------------------------------------------
#define PFD 8   // prefetch depth in 8-t groups
__global__ __launch_bounds__(512) void k45(
    const unsigned short* __restrict__ sigT, const float* __restrict__ W2,
    float* __restrict__ out)
{
    __shared__ unsigned short Ul[512 * 128];   // 128 KB

    const int tid = threadIdx.x;
    const int b = blockIdx.x;

    if (tid < 128) {
        const int p = tid;
        const int pc = (p >> 3) << 3;          // chunk base (ushorts)
        const int pw = p & 7;
        const ushort8v* sx = (const ushort8v*)(sigT + (((size_t)(b * NBS + 3 * p    )) << 9));
        const ushort8v* sy = (const ushort8v*)(sigT + (((size_t)(b * NBS + 3 * p + 1)) << 9));
        const ushort8v* sz = (const ushort8v*)(sigT + (((size_t)(b * NBS + 3 * p + 2)) << 9));

        ushort8v px[PFD], py[PFD], pz[PFD];
#pragma unroll
        for (int g = 0; g < PFD; ++g) { px[g] = sx[g]; py[g] = sy[g]; pz[g] = sz[g]; }

        float u = 10.0f;   // SIG_Y + HARD*0
#pragma unroll 8
        for (int g = 0; g < 64 - PFD; ++g) {
            const int sl = g & (PFD - 1);
            ushort8v vx = px[sl], vy = py[sl], vz = pz[sl];
            px[sl] = sx[g + PFD]; py[sl] = sy[g + PFD]; pz[sl] = sz[g + PFD];
#pragma unroll
            for (int i = 0; i < 8; ++i) {
                float sxx = bf2f(vx[i]), syy = bf2f(vy[i]), txy = bf2f(vz[i]);
                float e = sxx*sxx - sxx*syy + syy*syy + 3.0f*txy*txy + 1e-12f;
                float seq = sqrtf(e);
                u = fmaf(fmaxf(seq - u, 0.0f), HOVER, u);
                const int t = g * 8 + i;
                Ul[t * 128 + (pc ^ ((t & 15) << 3)) + pw] = f2bf(u);
            }
        }
#pragma unroll
        for (int g = 64 - PFD; g < 64; ++g) {
            const int sl = g & (PFD - 1);
            ushort8v vx = px[sl], vy = py[sl], vz = pz[sl];
#pragma unroll
            for (int i = 0; i < 8; ++i) {
                float sxx = bf2f(vx[i]), syy = bf2f(vy[i]), txy = bf2f(vz[i]);
                float e = sxx*sxx - sxx*syy + syy*syy + 3.0f*txy*txy + 1e-12f;
                float seq = sqrtf(e);
                u = fmaf(fmaxf(seq - u, 0.0f), HOVER, u);
                const int t = g * 8 + i;
                Ul[t * 128 + (pc ^ ((t & 15) << 3)) + pw] = f2bf(u);
            }
        }
    }
    __syncthreads();

    // phase 2: thread t = tid
    const int t = tid;
    const unsigned short* sb = sigT + (((size_t)(b * NBS)) << 9) + t;

    float acc[6] = {0, 0, 0, 0, 0, 0};
#pragma unroll 2
    for (int c = 0; c < 16; ++c) {
        ushort8v uu = *(const ushort8v*)&Ul[t * 128 + ((c << 3) ^ ((t & 15) << 3))];
#pragma unroll
        for (int i = 0; i < 8; ++i) {
            const int p = c * 8 + i;
            float sxx = bf2f(sb[(size_t)(3 * p    ) << 9]);
            float syy = bf2f(sb[(size_t)(3 * p + 1) << 9]);
            float txy = bf2f(sb[(size_t)(3 * p + 2) << 9]);
            float u   = bf2f(uu[i]);
            float e = sxx*sxx - sxx*syy + syy*syy + 3.0f*txy*txy + 1e-12f;
            float scale = fminf(1.0f, u * rsqrtf(e));
            float fx = sxx * scale, fy = syy * scale, fz = txy * scale;
#pragma unroll
            for (int o = 0; o < 6; ++o) {
                acc[o] = fmaf(fx, W2[o * NBS + 3 * p    ], acc[o]);
                acc[o] = fmaf(fy, W2[o * NBS + 3 * p + 1], acc[o]);
                acc[o] = fmaf(fz, W2[o * NBS + 3 * p + 2], acc[o]);
            }
        }
    }

    float* op = out + ((size_t)(b * NT + t)) * 6;
#pragma unroll
    for (int o = 0; o < 6; ++o) {
        float z = acc[o];
        op[o] = fmaxf(z, 0.0f) + log1pf(expf(-fabsf(z)));
    }
}

// ---------------------------------------------------------------------------
extern "C" void kernel_launch(void* const* d_in, const int* in_sizes, int n_in,
                              void* d_out, int out_size, void* d_ws, size_t ws_size,
                              hipStream_t stream)
{
    const float* x   = (const float*)d_in[0];
    const float* W11 = (const float*)d_in[1];
    const float* b11 = (const float*)d_in[2];
    const float* W12 = (const float*)d_in[3];
    const float* W2  = (const float*)d_in[4];
    float* out = (float*)d_out;

    // ws: dnT 16MB @0 | sigT 96MB @32MB | totals 512KB @128MB
    unsigned short* dnT = (unsigned short*)d_ws;
    unsigned short* sigT = (unsigned short*)((char*)d_ws + (size_t)NROWS * NCOH * sizeof(float));
    float* totals = (float*)((char*)d_ws + (size_t)128 * 1024 * 1024);

    k0_w12<<<(2 * NBS * NIN) / 256, 256, 0, stream>>>(W12);
    k0b_w11<<<128, 256, 0, stream>>>(W11);
    k1_fc11<<<NROWS / 128, 256, 0, stream>>>(x, b11, dnT);
    k2a<<<NB * 8, 64, 0, stream>>>(dnT, totals);
    k2b<<<NB * 8, 64, 0, stream>>>(dnT, totals);
    k3_mfma<<<3072, 256, 0, stream>>>(sigT);
    k45<<<NB, 512, 0, stream>>>(sigT, W2, out);
}

// Round 7
// 263.284 us; speedup vs baseline: 1.1704x; 1.1704x over previous
//
#include <hip/hip_runtime.h>
#include <hip/hip_bf16.h>
#include <math.h>

// Problem dims
#define NB 256
#define NT 512
#define NF 128
#define NCOH 64         // coh_pts
#define NIN 192         // F + coh_pts
#define NBS 384         // 3*bulk_pts
#define NROWS (NB*NT)   // 131072

// Material constants (match fp64->fp32 of reference)
#define C11 1098.9010989010989f
#define C12 329.67032967032966f
#define C33 384.61538461538464f
#define H3G 1253.8461538461538f   // 3*G + HARD
#define HOVER 0.07975460122699386f // HARD / (3*G + HARD)

typedef __attribute__((ext_vector_type(8))) short bf16x8;   // 8 bf16 = 4 VGPR
typedef __attribute__((ext_vector_type(4))) float f32x4;    // MFMA acc
typedef __attribute__((ext_vector_type(8))) unsigned short ushort8v;
typedef __attribute__((ext_vector_type(4))) unsigned short ushort4v;

// s_waitcnt with only vmcnt constrained (expcnt=7, lgkmcnt=15 = no-wait)
#define WAITCNT_VM(N) __builtin_amdgcn_s_waitcnt(0x0F70 | ((N) & 15) | (((N) >> 4) << 14))

// A operand (x | dmg), bf16. TILED layout: [kchunk 0..5][row 0..NROWS)[32]
// so one 16-row fragment = 1 KB contiguous (wave-coalesced global load).
#define PS ((size_t)NROWS * 32)     // plane stride in ushorts
__device__ unsigned short g_Ahi[6 * PS];
// B (D-folded W12, hi+lo split) in FRAGMENT-MAJOR order:
// [nblk 0..5][kc 0..5][part 0..1][nf 0..3][lane 0..63][8]
__device__ unsigned short g_Bres[2 * NBS * NIN];
// W11 fragment-major hi/lo: [kc 0..3][part 0..1][nf 0..7][lane 0..63][8] = 64 KB
__device__ unsigned short g_W11res[32768];

static __device__ __forceinline__ unsigned short f2bf(float v) {
    __hip_bfloat16 h = __float2bfloat16(v);
    return *reinterpret_cast<unsigned short*>(&h);
}
static __device__ __forceinline__ float bf2f(unsigned short u) {
    unsigned int x = ((unsigned int)u) << 16;
    return *reinterpret_cast<float*>(&x);
}
static __device__ __forceinline__ void async_copy16(const void* g, void* l) {
    __builtin_amdgcn_global_load_lds(
        (const __attribute__((address_space(1))) unsigned int*)g,
        (__attribute__((address_space(3))) unsigned int*)l, 16, 0, 0);
}

// ---------------------------------------------------------------------------
// K0: fold plane-stress D into W12, split bf16 hi/lo, emit fragment-major.
// ---------------------------------------------------------------------------
__global__ __launch_bounds__(256) void k0_w12(const float* __restrict__ W12)
{
    const int idx = blockIdx.x * 256 + threadIdx.x;   // < 294912
    const int e    = idx & 7;
    const int l    = (idx >> 3) & 63;
    const int nf   = (idx >> 9) & 3;
    const int part = (idx >> 11) & 1;
    const int kc   = (idx >> 12) % 6;
    const int nblk = idx / 24576;                     // 6*4096
    const int n = nblk * 64 + nf * 16 + (l & 15);
    const int k = kc * 32 + (l >> 4) * 8 + e;
    const int p = n / 3, j = n - 3 * p;
    const float* w = W12 + (size_t)(3 * p) * NIN;
    float v;
    if (j == 0)      v = C11 * w[k]           + C12 * w[NIN + k];
    else if (j == 1) v = C12 * w[k]           + C11 * w[NIN + k];
    else             v = C33 * w[2 * NIN + k];
    unsigned short h = f2bf(v);
    g_Bres[idx] = part ? f2bf(v - bf2f(h)) : h;
}

// ---------------------------------------------------------------------------
// K0b: W11 -> fragment-major bf16 hi/lo (for k1's MFMA).
// ---------------------------------------------------------------------------
__global__ __launch_bounds__(256) void k0b_w11(const float* __restrict__ W11)
{
    const int idx = blockIdx.x * 256 + threadIdx.x;   // < 32768
    const int e    = idx & 7;
    const int l    = (idx >> 3) & 63;
    const int nf   = (idx >> 9) & 7;
    const int part = (idx >> 12) & 1;
    const int kc   = idx >> 13;                       // 0..3
    const int n = nf * 16 + (l & 15);
    const int k = kc * 32 + (l >> 4) * 8 + e;
    const float v = W11[(size_t)n * NF + k];
    unsigned short h = f2bf(v);
    g_W11res[idx] = part ? f2bf(v - bf2f(h)) : h;
}

// ---------------------------------------------------------------------------
// K1 (fused kx+fc11): reads x fp32 directly in fragment order, converts
// hi/lo bf16 in-register, stores hi planes 0..3 for k3, runs the W11 MFMA.
// C = Wh*xh + Wl*xh + Wh*xl. dnew computed in-register, stored bf16 c-major.
// ---------------------------------------------------------------------------
__global__ __launch_bounds__(256) void k1_fc11(
    const float* __restrict__ x, const float* __restrict__ b11,
    unsigned short* __restrict__ dnT)
{
    __shared__ unsigned short Ws[32768];   // 64 KB

    const int tid = threadIdx.x;
    const int lane = tid & 63, w = tid >> 6;
    const int fr = lane & 15, fq = lane >> 4;
    const int xbase = blockIdx.x * 128 + w * 32;

    // stage W11res (64 KB linear copy)
#pragma unroll
    for (int i = 0; i < 16; ++i)
        async_copy16((const char*)g_W11res + tid * 16 + i * 4096,
                     (char*)Ws + tid * 16 + i * 4096);

    f32x4 acc[8][2];
#pragma unroll
    for (int q = 0; q < 8; ++q)
#pragma unroll
        for (int f = 0; f < 2; ++f) acc[q][f] = (f32x4){0.f, 0.f, 0.f, 0.f};

    WAITCNT_VM(0);
    __builtin_amdgcn_s_barrier();

#pragma unroll
    for (int kc = 0; kc < 4; ++kc) {
        bf16x8 ah[2], al[2];
#pragma unroll
        for (int f = 0; f < 2; ++f) {
            const int row = xbase + f * 16 + fr;
            const float* xs = x + (size_t)row * NF + kc * 32 + fq * 8;
            float4 v0 = ((const float4*)xs)[0];
            float4 v1 = ((const float4*)xs)[1];
            float v[8] = {v0.x, v0.y, v0.z, v0.w, v1.x, v1.y, v1.z, v1.w};
            ushort8v h, lo;
#pragma unroll
            for (int i = 0; i < 8; ++i) {
                h[i]  = f2bf(v[i]);
                lo[i] = f2bf(v[i] - bf2f(h[i]));
            }
            *(ushort8v*)(g_Ahi + (size_t)kc * PS + (size_t)row * 32 + fq * 8) = h;
            ah[f] = *reinterpret_cast<bf16x8*>(&h);
            al[f] = *reinterpret_cast<bf16x8*>(&lo);
        }
#pragma unroll
        for (int q = 0; q < 8; ++q) {
            bf16x8 wh = *(const bf16x8*)&Ws[(kc * 16 + q) * 512 + lane * 8];
            bf16x8 wl = *(const bf16x8*)&Ws[(kc * 16 + 8 + q) * 512 + lane * 8];
#pragma unroll
            for (int f = 0; f < 2; ++f) {
                acc[q][f] = __builtin_amdgcn_mfma_f32_16x16x32_bf16(
                    wh, ah[f], acc[q][f], 0, 0, 0);
                acc[q][f] = __builtin_amdgcn_mfma_f32_16x16x32_bf16(
                    wl, ah[f], acc[q][f], 0, 0, 0);
                acc[q][f] = __builtin_amdgcn_mfma_f32_16x16x32_bf16(
                    wh, al[f], acc[q][f], 0, 0, 0);
            }
        }
    }

#pragma unroll
    for (int q = 0; q < 8; ++q) {
        float4 bv = *(const float4*)(b11 + q * 16 + fq * 4);
#pragma unroll
        for (int f = 0; f < 2; ++f) {
            const int xrow = xbase + f * 16 + fr;
            float z[4] = {acc[q][f][0] + bv.x, acc[q][f][1] + bv.y,
                          acc[q][f][2] + bv.z, acc[q][f][3] + bv.w};
#pragma unroll
            for (int pr = 0; pr < 2; ++pr) {
                float jn = fmaxf(z[2 * pr], 0.0f);
                float zs = z[2 * pr + 1];
                float js = (zs > 0.0f) ? zs : 0.01f * zs;
                float delta = sqrtf(jn * jn + js * js + 1e-12f);
                float dn = 0.1f * (delta - 0.01f) / (fmaxf(delta, 1e-12f) * 0.09f);
                dn = fminf(fmaxf(dn, 0.0f), 1.0f);
                dnT[(size_t)(q * 8 + fq * 2 + pr) * NROWS + xrow] = f2bf(dn);
            }
        }
    }
}

// ---------------------------------------------------------------------------
// K2 (two-phase parallel cummax on c-major bf16 dnT).
// ---------------------------------------------------------------------------
__global__ __launch_bounds__(64) void k2a(const unsigned short* __restrict__ dnT,
                                          float* __restrict__ totals)
{
    const int b = blockIdx.x >> 3, seg = blockIdx.x & 7;
    const int c = threadIdx.x;
    const ushort8v* p = (const ushort8v*)(dnT + (size_t)c * NROWS + b * NT + seg * 64);
    float m = 0.0f;
#pragma unroll
    for (int g = 0; g < 8; ++g) {
        ushort8v v = p[g];
#pragma unroll
        for (int i = 0; i < 8; ++i) m = fmaxf(m, bf2f(v[i]));
    }
    totals[(size_t)(b * 8 + seg) * 64 + c] = m;
}

__global__ __launch_bounds__(64) void k2b(const unsigned short* __restrict__ dnT,
                                          const float* __restrict__ totals)
{
    const int b = blockIdx.x >> 3, seg = blockIdx.x & 7;
    const int c = threadIdx.x;
    float carry = 0.0f;
    for (int s = 0; s < seg; ++s)
        carry = fmaxf(carry, totals[(size_t)(b * 8 + s) * 64 + c]);
    const ushort8v* p = (const ushort8v*)(dnT + (size_t)c * NROWS + b * NT + seg * 64);
    unsigned short* ah = g_Ahi + (size_t)(4 + (c >> 5)) * PS
                       + (size_t)(b * NT + seg * 64) * 32 + (c & 31);
    float m = carry;
#pragma unroll
    for (int g = 0; g < 8; ++g) {
        ushort8v v = p[g];
#pragma unroll
        for (int i = 0; i < 8; ++i) {
            m = fmaxf(m, bf2f(v[i]));
            ah[(size_t)(g * 8 + i) * 32] = f2bf(m);
        }
    }
}

// ---------------------------------------------------------------------------
// K3: sig_tr = A @ B^T via MFMA, C = Ahi*(Bhi + Blo). B LDS-resident
// fragment-major (48 KB, zero conflicts, no loop barriers); A from global,
// double-buffered. XCD swizzle: 6 n-blocks of one m-tile share an XCD.
// Epilogue: acc -> LDS transpose tile (reusing Bs) -> fully-coalesced
// global stores (each wave-store = two contiguous 512 B runs).
// ---------------------------------------------------------------------------
__global__ __launch_bounds__(256, 3) void k3_mfma(unsigned short* __restrict__ sigT)
{
    __shared__ unsigned short Bs[24576];   // 48 KB: [kc][part][nf][lane][8]

    const int tid = threadIdx.x;
    const int lane = tid & 63, w = tid >> 6;
    const int id = blockIdx.x;
    const int sw = (id & 7) * 384 + (id >> 3);
    const int nblk = sw % 6;
    const int m0 = (sw / 6) * 256;
    const int n0 = nblk * 64;
    const int wm = w * 64;
    const int fr = lane & 15, fq = lane >> 4;

    const size_t abase = (size_t)(m0 + wm + fr) * 32 + fq * 8;

    bf16x8 a0[4], a1[4];
#pragma unroll
    for (int mi = 0; mi < 4; ++mi)
        a0[mi] = *(const bf16x8*)(g_Ahi + abase + mi * 512);

    {
        const char* bsrc = (const char*)g_Bres + (size_t)nblk * 49152;
#pragma unroll
        for (int i = 0; i < 12; ++i)
            async_copy16(bsrc + tid * 16 + i * 4096, (char*)Bs + tid * 16 + i * 4096);
    }
    WAITCNT_VM(0);
    __builtin_amdgcn_s_barrier();

    f32x4 acc[4][4];
#pragma unroll
    for (int mi = 0; mi < 4; ++mi)
#pragma unroll
        for (int ni = 0; ni < 4; ++ni) acc[mi][ni] = (f32x4){0.f, 0.f, 0.f, 0.f};

#pragma unroll
    for (int c = 0; c < 6; ++c) {
        bf16x8* acur = (c & 1) ? a1 : a0;
        bf16x8* anxt = (c & 1) ? a0 : a1;
        if (c < 5) {
#pragma unroll
            for (int mi = 0; mi < 4; ++mi)
                anxt[mi] = *(const bf16x8*)(g_Ahi + (size_t)(c + 1) * PS
                                            + abase + mi * 512);
        }
        bf16x8 bh[4], bl[4];
#pragma unroll
        for (int ni = 0; ni < 4; ++ni) {
            bh[ni] = *(const bf16x8*)&Bs[((c * 8 + ni) << 9) + lane * 8];
            bl[ni] = *(const bf16x8*)&Bs[((c * 8 + 4 + ni) << 9) + lane * 8];
        }
#pragma unroll
        for (int mi = 0; mi < 4; ++mi)
#pragma unroll
            for (int ni = 0; ni < 4; ++ni) {
                acc[mi][ni] = __builtin_amdgcn_mfma_f32_16x16x32_bf16(
                    acur[mi], bh[ni], acc[mi][ni], 0, 0, 0);
                acc[mi][ni] = __builtin_amdgcn_mfma_f32_16x16x32_bf16(
                    acur[mi], bl[ni], acc[mi][ni], 0, 0, 0);
            }
    }

    // ---- epilogue: LDS transpose (reuse Bs) then coalesced stores ----
    __syncthreads();                       // all waves done reading Bs
    unsigned short* T = Bs;                // [64 cols][272] (row 544 B, 16B-aligned)
#pragma unroll
    for (int mi = 0; mi < 4; ++mi)
#pragma unroll
        for (int ni = 0; ni < 4; ++ni) {
            const int cIdx = ni * 16 + fr;
            const int tloc = wm + mi * 16 + fq * 4;
            ushort4v h;
#pragma unroll
            for (int r = 0; r < 4; ++r) h[r] = f2bf(acc[mi][ni][r]);
            *(ushort4v*)&T[cIdx * 272 + tloc] = h;
        }
    __syncthreads();

    const int b_idx = m0 >> 9;
    const int tq = lane & 31, c2 = lane >> 5;
    const size_t colbase = (((size_t)(b_idx * NBS + n0)) << 9) + (m0 & 511);
#pragma unroll
    for (int it = 0; it < 8; ++it) {
        const int cc = w * 16 + it * 2 + c2;
        ushort8v v = *(const ushort8v*)&T[cc * 272 + tq * 8];
        *(ushort8v*)(sigT + colbase + ((size_t)cc << 9) + tq * 8) = v;
    }
}

// ---------------------------------------------------------------------------
// K4: yield-stress scan u' = u + (H/(3G+H))*max(seq-u, 0), u0 = SIG_Y.
// 3 contiguous bf16 t-streams per chain, depth-8 register prefetch,
// writes only u (bf16). Scale recovered in k5 as min(1, u/seq).
// ---------------------------------------------------------------------------
#define PFD 8   // prefetch depth in 8-t groups
__global__ __launch_bounds__(128) void k4_scan(
    const unsigned short* __restrict__ sigT, unsigned short* __restrict__ uT)
{
    const int b = blockIdx.x;
    const int p = threadIdx.x;
    const ushort8v* sx = (const ushort8v*)(sigT + (((size_t)(b * NBS + 3 * p    )) << 9));
    const ushort8v* sy = (const ushort8v*)(sigT + (((size_t)(b * NBS + 3 * p + 1)) << 9));
    const ushort8v* sz = (const ushort8v*)(sigT + (((size_t)(b * NBS + 3 * p + 2)) << 9));
    ushort8v* uo = (ushort8v*)(uT + (((size_t)(b * 128 + p)) << 9));

    ushort8v px[PFD], py[PFD], pz[PFD];
#pragma unroll
    for (int g = 0; g < PFD; ++g) { px[g] = sx[g]; py[g] = sy[g]; pz[g] = sz[g]; }

    float u = 10.0f;   // SIG_Y + HARD*0
#pragma unroll 8
    for (int g = 0; g < 64 - PFD; ++g) {
        const int sl = g & (PFD - 1);
        ushort8v vx = px[sl], vy = py[sl], vz = pz[sl];
        px[sl] = sx[g + PFD]; py[sl] = sy[g + PFD]; pz[sl] = sz[g + PFD];
        ushort8v ov;
#pragma unroll
        for (int i = 0; i < 8; ++i) {
            float sxx = bf2f(vx[i]), syy = bf2f(vy[i]), txy = bf2f(vz[i]);
            float e = sxx*sxx - sxx*syy + syy*syy + 3.0f*txy*txy + 1e-12f;
            float seq = sqrtf(e);
            u = fmaf(fmaxf(seq - u, 0.0f), HOVER, u);
            ov[i] = f2bf(u);
        }
        uo[g] = ov;
    }
#pragma unroll
    for (int g = 64 - PFD; g < 64; ++g) {
        const int sl = g & (PFD - 1);
        ushort8v vx = px[sl], vy = py[sl], vz = pz[sl];
        ushort8v ov;
#pragma unroll
        for (int i = 0; i < 8; ++i) {
            float sxx = bf2f(vx[i]), syy = bf2f(vy[i]), txy = bf2f(vz[i]);
            float e = sxx*sxx - sxx*syy + syy*syy + 3.0f*txy*txy + 1e-12f;
            float seq = sqrtf(e);
            u = fmaf(fmaxf(seq - u, 0.0f), HOVER, u);
            ov[i] = f2bf(u);
        }
        uo[g] = ov;
    }
}

// ---------------------------------------------------------------------------
// K5: thread per t on t-major layout. Recompute seq, scale = min(1, u/seq),
// apply, GEMM 384->6 against LDS W2, softplus.
// ---------------------------------------------------------------------------
__global__ __launch_bounds__(256) void k5_out(
    const unsigned short* __restrict__ sigT, const unsigned short* __restrict__ uT,
    const float* __restrict__ W2, float* __restrict__ out)
{
    __shared__ float W2s[6][NBS];
    const int tid = threadIdx.x;
    for (int i = tid; i < 6 * NBS; i += 256) W2s[i / NBS][i % NBS] = W2[i];
    __syncthreads();

    const int b = blockIdx.x >> 1;
    const int t = (blockIdx.x & 1) * 256 + tid;
    const unsigned short* sb = sigT + (((size_t)b * NBS) << 9) + t;
    const unsigned short* ub = uT + (((size_t)b * 128) << 9) + t;

    float acc[6] = {0, 0, 0, 0, 0, 0};
#pragma unroll 4
    for (int p = 0; p < 128; ++p) {
        float sxx = bf2f(sb[(size_t)(3 * p    ) << 9]);
        float syy = bf2f(sb[(size_t)(3 * p + 1) << 9]);
        float txy = bf2f(sb[(size_t)(3 * p + 2) << 9]);
        float u   = bf2f(ub[(size_t)p << 9]);
        float e = sxx*sxx - sxx*syy + syy*syy + 3.0f*txy*txy + 1e-12f;
        float scale = fminf(1.0f, u * rsqrtf(e));
        float fx = sxx * scale, fy = syy * scale, fz = txy * scale;
#pragma unroll
        for (int o = 0; o < 6; ++o) {
            acc[o] = fmaf(fx, W2s[o][3 * p    ], acc[o]);
            acc[o] = fmaf(fy, W2s[o][3 * p + 1], acc[o]);
            acc[o] = fmaf(fz, W2s[o][3 * p + 2], acc[o]);
        }
    }

    float* op = out + ((size_t)(b * NT + t)) * 6;
#pragma unroll
    for (int o = 0; o < 6; ++o) {
        float z = acc[o];
        op[o] = fmaxf(z, 0.0f) + log1pf(expf(-fabsf(z)));
    }
}

// ---------------------------------------------------------------------------
extern "C" void kernel_launch(void* const* d_in, const int* in_sizes, int n_in,
                              void* d_out, int out_size, void* d_ws, size_t ws_size,
                              hipStream_t stream)
{
    const float* x   = (const float*)d_in[0];
    const float* W11 = (const float*)d_in[1];
    const float* b11 = (const float*)d_in[2];
    const float* W12 = (const float*)d_in[3];
    const float* W2  = (const float*)d_in[4];
    float* out = (float*)d_out;

    // ws: dnT 16MB @0 (dead after k2b -> region reused as uT 32MB) |
    //     sigT 96MB @32MB | totals 512KB @128MB
    unsigned short* dnT = (unsigned short*)d_ws;
    unsigned short* uT = (unsigned short*)d_ws;
    unsigned short* sigT = (unsigned short*)((char*)d_ws + (size_t)NROWS * NCOH * sizeof(float));
    float* totals = (float*)((char*)d_ws + (size_t)128 * 1024 * 1024);

    k0_w12<<<(2 * NBS * NIN) / 256, 256, 0, stream>>>(W12);
    k0b_w11<<<128, 256, 0, stream>>>(W11);
    k1_fc11<<<NROWS / 128, 256, 0, stream>>>(x, b11, dnT);
    k2a<<<NB * 8, 64, 0, stream>>>(dnT, totals);
    k2b<<<NB * 8, 64, 0, stream>>>(dnT, totals);
    k3_mfma<<<3072, 256, 0, stream>>>(sigT);
    k4_scan<<<NB, 128, 0, stream>>>(sigT, uT);
    k5_out<<<NROWS / 256, 256, 0, stream>>>(sigT, uT, W2, out);
}

// Round 8
// 255.937 us; speedup vs baseline: 1.2040x; 1.0287x over previous
//
#include <hip/hip_runtime.h>
#include <hip/hip_bf16.h>
#include <math.h>

// Problem dims
#define NB 256
#define NT 512
#define NF 128
#define NCOH 64         // coh_pts
#define NIN 192         // F + coh_pts
#define NBS 384         // 3*bulk_pts
#define NROWS (NB*NT)   // 131072

// Material constants (match fp64->fp32 of reference)
#define C11 1098.9010989010989f
#define C12 329.67032967032966f
#define C33 384.61538461538464f
#define H3G 1253.8461538461538f   // 3*G + HARD
#define HOVER 0.07975460122699386f // HARD / (3*G + HARD)

typedef __attribute__((ext_vector_type(8))) short bf16x8;   // 8 bf16 = 4 VGPR
typedef __attribute__((ext_vector_type(4))) float f32x4;    // MFMA acc
typedef __attribute__((ext_vector_type(8))) unsigned short ushort8v;
typedef __attribute__((ext_vector_type(4))) unsigned short ushort4v;

// s_waitcnt with only vmcnt constrained (expcnt=7, lgkmcnt=15 = no-wait)
#define WAITCNT_VM(N) __builtin_amdgcn_s_waitcnt(0x0F70 | ((N) & 15) | (((N) >> 4) << 14))

// A operand (x | dmg), bf16. TILED layout: [kchunk 0..5][row 0..NROWS)[32]
// so one 16-row fragment = 1 KB contiguous (wave-coalesced global load).
#define PS ((size_t)NROWS * 32)     // plane stride in ushorts
__device__ unsigned short g_Ahi[6 * PS];
// B (D-folded W12, hi+lo split) in FRAGMENT-MAJOR order:
// [nblk 0..5][kc 0..5][part 0..1][nf 0..3][lane 0..63][8]
__device__ unsigned short g_Bres[2 * NBS * NIN];
// W11 fragment-major hi/lo: [kc 0..3][part 0..1][nf 0..7][lane 0..63][8] = 64 KB
__device__ unsigned short g_W11res[32768];

static __device__ __forceinline__ unsigned short f2bf(float v) {
    __hip_bfloat16 h = __float2bfloat16(v);
    return *reinterpret_cast<unsigned short*>(&h);
}
static __device__ __forceinline__ float bf2f(unsigned short u) {
    unsigned int x = ((unsigned int)u) << 16;
    return *reinterpret_cast<float*>(&x);
}
static __device__ __forceinline__ void async_copy16(const void* g, void* l) {
    __builtin_amdgcn_global_load_lds(
        (const __attribute__((address_space(1))) unsigned int*)g,
        (__attribute__((address_space(3))) unsigned int*)l, 16, 0, 0);
}

// ---------------------------------------------------------------------------
// K0: fold plane-stress D into W12, split bf16 hi/lo, emit fragment-major.
// ---------------------------------------------------------------------------
__global__ __launch_bounds__(256) void k0_w12(const float* __restrict__ W12)
{
    const int idx = blockIdx.x * 256 + threadIdx.x;   // < 294912
    const int e    = idx & 7;
    const int l    = (idx >> 3) & 63;
    const int nf   = (idx >> 9) & 3;
    const int part = (idx >> 11) & 1;
    const int kc   = (idx >> 12) % 6;
    const int nblk = idx / 24576;                     // 6*4096
    const int n = nblk * 64 + nf * 16 + (l & 15);
    const int k = kc * 32 + (l >> 4) * 8 + e;
    const int p = n / 3, j = n - 3 * p;
    const float* w = W12 + (size_t)(3 * p) * NIN;
    float v;
    if (j == 0)      v = C11 * w[k]           + C12 * w[NIN + k];
    else if (j == 1) v = C12 * w[k]           + C11 * w[NIN + k];
    else             v = C33 * w[2 * NIN + k];
    unsigned short h = f2bf(v);
    g_Bres[idx] = part ? f2bf(v - bf2f(h)) : h;
}

// ---------------------------------------------------------------------------
// K0b: W11 -> fragment-major bf16 hi/lo (for k1's MFMA).
// ---------------------------------------------------------------------------
__global__ __launch_bounds__(256) void k0b_w11(const float* __restrict__ W11)
{
    const int idx = blockIdx.x * 256 + threadIdx.x;   // < 32768
    const int e    = idx & 7;
    const int l    = (idx >> 3) & 63;
    const int nf   = (idx >> 9) & 7;
    const int part = (idx >> 12) & 1;
    const int kc   = idx >> 13;                       // 0..3
    const int n = nf * 16 + (l & 15);
    const int k = kc * 32 + (l >> 4) * 8 + e;
    const float v = W11[(size_t)n * NF + k];
    unsigned short h = f2bf(v);
    g_W11res[idx] = part ? f2bf(v - bf2f(h)) : h;
}

// ---------------------------------------------------------------------------
// K1 (fused kx+fc11): reads x fp32 directly in fragment order, converts
// hi/lo bf16 in-register, stores hi planes 0..3 for k3, runs the W11 MFMA.
// C = Wh*xh + Wl*xh + Wh*xl. dnew computed in-register, stored bf16 c-major.
// ---------------------------------------------------------------------------
__global__ __launch_bounds__(256) void k1_fc11(
    const float* __restrict__ x, const float* __restrict__ b11,
    unsigned short* __restrict__ dnT)
{
    __shared__ unsigned short Ws[32768];   // 64 KB

    const int tid = threadIdx.x;
    const int lane = tid & 63, w = tid >> 6;
    const int fr = lane & 15, fq = lane >> 4;
    const int xbase = blockIdx.x * 128 + w * 32;

    // stage W11res (64 KB linear copy)
#pragma unroll
    for (int i = 0; i < 16; ++i)
        async_copy16((const char*)g_W11res + tid * 16 + i * 4096,
                     (char*)Ws + tid * 16 + i * 4096);

    f32x4 acc[8][2];
#pragma unroll
    for (int q = 0; q < 8; ++q)
#pragma unroll
        for (int f = 0; f < 2; ++f) acc[q][f] = (f32x4){0.f, 0.f, 0.f, 0.f};

    WAITCNT_VM(0);
    __builtin_amdgcn_s_barrier();

#pragma unroll
    for (int kc = 0; kc < 4; ++kc) {
        bf16x8 ah[2], al[2];
#pragma unroll
        for (int f = 0; f < 2; ++f) {
            const int row = xbase + f * 16 + fr;
            const float* xs = x + (size_t)row * NF + kc * 32 + fq * 8;
            float4 v0 = ((const float4*)xs)[0];
            float4 v1 = ((const float4*)xs)[1];
            float v[8] = {v0.x, v0.y, v0.z, v0.w, v1.x, v1.y, v1.z, v1.w};
            ushort8v h, lo;
#pragma unroll
            for (int i = 0; i < 8; ++i) {
                h[i]  = f2bf(v[i]);
                lo[i] = f2bf(v[i] - bf2f(h[i]));
            }
            *(ushort8v*)(g_Ahi + (size_t)kc * PS + (size_t)row * 32 + fq * 8) = h;
            ah[f] = *reinterpret_cast<bf16x8*>(&h);
            al[f] = *reinterpret_cast<bf16x8*>(&lo);
        }
#pragma unroll
        for (int q = 0; q < 8; ++q) {
            bf16x8 wh = *(const bf16x8*)&Ws[(kc * 16 + q) * 512 + lane * 8];
            bf16x8 wl = *(const bf16x8*)&Ws[(kc * 16 + 8 + q) * 512 + lane * 8];
#pragma unroll
            for (int f = 0; f < 2; ++f) {
                acc[q][f] = __builtin_amdgcn_mfma_f32_16x16x32_bf16(
                    wh, ah[f], acc[q][f], 0, 0, 0);
                acc[q][f] = __builtin_amdgcn_mfma_f32_16x16x32_bf16(
                    wl, ah[f], acc[q][f], 0, 0, 0);
                acc[q][f] = __builtin_amdgcn_mfma_f32_16x16x32_bf16(
                    wh, al[f], acc[q][f], 0, 0, 0);
            }
        }
    }

#pragma unroll
    for (int q = 0; q < 8; ++q) {
        float4 bv = *(const float4*)(b11 + q * 16 + fq * 4);
#pragma unroll
        for (int f = 0; f < 2; ++f) {
            const int xrow = xbase + f * 16 + fr;
            float z[4] = {acc[q][f][0] + bv.x, acc[q][f][1] + bv.y,
                          acc[q][f][2] + bv.z, acc[q][f][3] + bv.w};
#pragma unroll
            for (int pr = 0; pr < 2; ++pr) {
                float jn = fmaxf(z[2 * pr], 0.0f);
                float zs = z[2 * pr + 1];
                float js = (zs > 0.0f) ? zs : 0.01f * zs;
                float delta = sqrtf(jn * jn + js * js + 1e-12f);
                float dn = 0.1f * (delta - 0.01f) / (fmaxf(delta, 1e-12f) * 0.09f);
                dn = fminf(fmaxf(dn, 0.0f), 1.0f);
                dnT[(size_t)(q * 8 + fq * 2 + pr) * NROWS + xrow] = f2bf(dn);
            }
        }
    }
}

// ---------------------------------------------------------------------------
// K2 (two-phase parallel cummax on c-major bf16 dnT).
// ---------------------------------------------------------------------------
__global__ __launch_bounds__(64) void k2a(const unsigned short* __restrict__ dnT,
                                          float* __restrict__ totals)
{
    const int b = blockIdx.x >> 3, seg = blockIdx.x & 7;
    const int c = threadIdx.x;
    const ushort8v* p = (const ushort8v*)(dnT + (size_t)c * NROWS + b * NT + seg * 64);
    float m = 0.0f;
#pragma unroll
    for (int g = 0; g < 8; ++g) {
        ushort8v v = p[g];
#pragma unroll
        for (int i = 0; i < 8; ++i) m = fmaxf(m, bf2f(v[i]));
    }
    totals[(size_t)(b * 8 + seg) * 64 + c] = m;
}

__global__ __launch_bounds__(64) void k2b(const unsigned short* __restrict__ dnT,
                                          const float* __restrict__ totals)
{
    const int b = blockIdx.x >> 3, seg = blockIdx.x & 7;
    const int c = threadIdx.x;
    float carry = 0.0f;
    for (int s = 0; s < seg; ++s)
        carry = fmaxf(carry, totals[(size_t)(b * 8 + s) * 64 + c]);
    const ushort8v* p = (const ushort8v*)(dnT + (size_t)c * NROWS + b * NT + seg * 64);
    unsigned short* ah = g_Ahi + (size_t)(4 + (c >> 5)) * PS
                       + (size_t)(b * NT + seg * 64) * 32 + (c & 31);
    float m = carry;
#pragma unroll
    for (int g = 0; g < 8; ++g) {
        ushort8v v = p[g];
#pragma unroll
        for (int i = 0; i < 8; ++i) {
            m = fmaxf(m, bf2f(v[i]));
            ah[(size_t)(g * 8 + i) * 32] = f2bf(m);
        }
    }
}

// ---------------------------------------------------------------------------
// K3: sig_tr = A @ B^T via MFMA, C = Ahi*(Bhi + Blo). B LDS-resident
// fragment-major (48 KB, zero conflicts, no loop barriers); A from global,
// double-buffered. XCD swizzle: 6 n-blocks of one m-tile share an XCD.
// Epilogue: acc -> LDS transpose tile (reusing Bs) -> fully-coalesced
// global stores (each wave-store = two contiguous 512 B runs).
// ---------------------------------------------------------------------------
__global__ __launch_bounds__(256, 3) void k3_mfma(unsigned short* __restrict__ sigT)
{
    __shared__ unsigned short Bs[24576];   // 48 KB: [kc][part][nf][lane][8]

    const int tid = threadIdx.x;
    const int lane = tid & 63, w = tid >> 6;
    const int id = blockIdx.x;
    const int sw = (id & 7) * 384 + (id >> 3);
    const int nblk = sw % 6;
    const int m0 = (sw / 6) * 256;
    const int n0 = nblk * 64;
    const int wm = w * 64;
    const int fr = lane & 15, fq = lane >> 4;

    const size_t abase = (size_t)(m0 + wm + fr) * 32 + fq * 8;

    bf16x8 a0[4], a1[4];
#pragma unroll
    for (int mi = 0; mi < 4; ++mi)
        a0[mi] = *(const bf16x8*)(g_Ahi + abase + mi * 512);

    {
        const char* bsrc = (const char*)g_Bres + (size_t)nblk * 49152;
#pragma unroll
        for (int i = 0; i < 12; ++i)
            async_copy16(bsrc + tid * 16 + i * 4096, (char*)Bs + tid * 16 + i * 4096);
    }
    WAITCNT_VM(0);
    __builtin_amdgcn_s_barrier();

    f32x4 acc[4][4];
#pragma unroll
    for (int mi = 0; mi < 4; ++mi)
#pragma unroll
        for (int ni = 0; ni < 4; ++ni) acc[mi][ni] = (f32x4){0.f, 0.f, 0.f, 0.f};

#pragma unroll
    for (int c = 0; c < 6; ++c) {
        bf16x8* acur = (c & 1) ? a1 : a0;
        bf16x8* anxt = (c & 1) ? a0 : a1;
        if (c < 5) {
#pragma unroll
            for (int mi = 0; mi < 4; ++mi)
                anxt[mi] = *(const bf16x8*)(g_Ahi + (size_t)(c + 1) * PS
                                            + abase + mi * 512);
        }
        bf16x8 bh[4], bl[4];
#pragma unroll
        for (int ni = 0; ni < 4; ++ni) {
            bh[ni] = *(const bf16x8*)&Bs[((c * 8 + ni) << 9) + lane * 8];
            bl[ni] = *(const bf16x8*)&Bs[((c * 8 + 4 + ni) << 9) + lane * 8];
        }
#pragma unroll
        for (int mi = 0; mi < 4; ++mi)
#pragma unroll
            for (int ni = 0; ni < 4; ++ni) {
                acc[mi][ni] = __builtin_amdgcn_mfma_f32_16x16x32_bf16(
                    acur[mi], bh[ni], acc[mi][ni], 0, 0, 0);
                acc[mi][ni] = __builtin_amdgcn_mfma_f32_16x16x32_bf16(
                    acur[mi], bl[ni], acc[mi][ni], 0, 0, 0);
            }
    }

    // ---- epilogue: LDS transpose (reuse Bs) then coalesced stores ----
    __syncthreads();                       // all waves done reading Bs
    unsigned short* T = Bs;                // [64 cols][272] (row 544 B, 16B-aligned)
#pragma unroll
    for (int mi = 0; mi < 4; ++mi)
#pragma unroll
        for (int ni = 0; ni < 4; ++ni) {
            const int cIdx = ni * 16 + fr;
            const int tloc = wm + mi * 16 + fq * 4;
            ushort4v h;
#pragma unroll
            for (int r = 0; r < 4; ++r) h[r] = f2bf(acc[mi][ni][r]);
            *(ushort4v*)&T[cIdx * 272 + tloc] = h;
        }
    __syncthreads();

    const int b_idx = m0 >> 9;
    const int tq = lane & 31, c2 = lane >> 5;
    const size_t colbase = (((size_t)(b_idx * NBS + n0)) << 9) + (m0 & 511);
#pragma unroll
    for (int it = 0; it < 8; ++it) {
        const int cc = w * 16 + it * 2 + c2;
        ushort8v v = *(const ushort8v*)&T[cc * 272 + tq * 8];
        *(ushort8v*)(sigT + colbase + ((size_t)cc << 9) + tq * 8) = v;
    }
}

// ---------------------------------------------------------------------------
// K4 (producer-consumer rewrite): block per b, 512 threads (8 waves).
// Waves 2..7 compute seq(t) in fp32 (parallel over t; coalesced 128B wave
// loads) into double-buffered LDS chunks of 64 t; waves 0..1 run the 128
// serial u-chains over chunk c while chunk c+1 is produced. XOR-swizzled
// LDS [p][t^(p&31)] -> both sides <=2-way (free). seq stays fp32 end-to-end
// -> u bit-identical to the previous serial kernel.
// ---------------------------------------------------------------------------
#define K4CH 64
__global__ __launch_bounds__(512) void k4_scan(
    const unsigned short* __restrict__ sigT, unsigned short* __restrict__ uT)
{
    __shared__ float Sq[2][128 * K4CH];   // 2 x 32 KB

    const int tid = threadIdx.x;
    const int b = blockIdx.x;
    const int w = tid >> 6;

    // prologue: produce seq chunk 0
    if (w >= 2) {
        for (int idx = tid - 128; idx < 128 * K4CH; idx += 384) {
            const int t = idx & (K4CH - 1);
            const int p = idx >> 6;
            const size_t cb = ((size_t)(b * NBS + 3 * p)) << 9;
            float sxx = bf2f(sigT[cb + t]);
            float syy = bf2f(sigT[cb + 512 + t]);
            float txy = bf2f(sigT[cb + 1024 + t]);
            float e = sxx*sxx - sxx*syy + syy*syy + 3.0f*txy*txy + 1e-12f;
            Sq[0][p * K4CH + (t ^ (p & 31))] = sqrtf(e);
        }
    }
    __syncthreads();

    float u = 10.0f;   // SIG_Y + HARD*0
    ushort8v* uo = (ushort8v*)(uT + (((size_t)(b * 128 + (tid & 127))) << 9));

#pragma unroll 1
    for (int c = 0; c < 8; ++c) {
        if (w < 2) {
            const int p = tid;                 // 0..127
            const float* S = &Sq[c & 1][p * K4CH];
            const int pk = p & 31;
#pragma unroll
            for (int g = 0; g < 8; ++g) {
                float sq[8];
#pragma unroll
                for (int i = 0; i < 8; ++i) sq[i] = S[(g * 8 + i) ^ pk];
                ushort8v ov;
#pragma unroll
                for (int i = 0; i < 8; ++i) {
                    u = fmaf(fmaxf(sq[i] - u, 0.0f), HOVER, u);
                    ov[i] = f2bf(u);
                }
                uo[c * 8 + g] = ov;
            }
        } else if (c < 7) {
            const int base = (c + 1) * K4CH;
            float* D = Sq[(c + 1) & 1];
            for (int idx = tid - 128; idx < 128 * K4CH; idx += 384) {
                const int t = idx & (K4CH - 1);
                const int p = idx >> 6;
                const size_t cb = ((size_t)(b * NBS + 3 * p)) << 9;
                const int tt = base + t;
                float sxx = bf2f(sigT[cb + tt]);
                float syy = bf2f(sigT[cb + 512 + tt]);
                float txy = bf2f(sigT[cb + 1024 + tt]);
                float e = sxx*sxx - sxx*syy + syy*syy + 3.0f*txy*txy + 1e-12f;
                D[p * K4CH + (t ^ (p & 31))] = sqrtf(e);
            }
        }
        __syncthreads();
    }
}

// ---------------------------------------------------------------------------
// K5: thread per t on t-major layout. Recompute seq, scale = min(1, u/seq),
// apply, GEMM 384->6 against LDS W2, softplus.
// ---------------------------------------------------------------------------
__global__ __launch_bounds__(256) void k5_out(
    const unsigned short* __restrict__ sigT, const unsigned short* __restrict__ uT,
    const float* __restrict__ W2, float* __restrict__ out)
{
    __shared__ float W2s[6][NBS];
    const int tid = threadIdx.x;
    for (int i = tid; i < 6 * NBS; i += 256) W2s[i / NBS][i % NBS] = W2[i];
    __syncthreads();

    const int b = blockIdx.x >> 1;
    const int t = (blockIdx.x & 1) * 256 + tid;
    const unsigned short* sb = sigT + (((size_t)b * NBS) << 9) + t;
    const unsigned short* ub = uT + (((size_t)b * 128) << 9) + t;

    float acc[6] = {0, 0, 0, 0, 0, 0};
#pragma unroll 4
    for (int p = 0; p < 128; ++p) {
        float sxx = bf2f(sb[(size_t)(3 * p    ) << 9]);
        float syy = bf2f(sb[(size_t)(3 * p + 1) << 9]);
        float txy = bf2f(sb[(size_t)(3 * p + 2) << 9]);
        float u   = bf2f(ub[(size_t)p << 9]);
        float e = sxx*sxx - sxx*syy + syy*syy + 3.0f*txy*txy + 1e-12f;
        float scale = fminf(1.0f, u * rsqrtf(e));
        float fx = sxx * scale, fy = syy * scale, fz = txy * scale;
#pragma unroll
        for (int o = 0; o < 6; ++o) {
            acc[o] = fmaf(fx, W2s[o][3 * p    ], acc[o]);
            acc[o] = fmaf(fy, W2s[o][3 * p + 1], acc[o]);
            acc[o] = fmaf(fz, W2s[o][3 * p + 2], acc[o]);
        }
    }

    float* op = out + ((size_t)(b * NT + t)) * 6;
#pragma unroll
    for (int o = 0; o < 6; ++o) {
        float z = acc[o];
        op[o] = fmaxf(z, 0.0f) + log1pf(expf(-fabsf(z)));
    }
}

// ---------------------------------------------------------------------------
extern "C" void kernel_launch(void* const* d_in, const int* in_sizes, int n_in,
                              void* d_out, int out_size, void* d_ws, size_t ws_size,
                              hipStream_t stream)
{
    const float* x   = (const float*)d_in[0];
    const float* W11 = (const float*)d_in[1];
    const float* b11 = (const float*)d_in[2];
    const float* W12 = (const float*)d_in[3];
    const float* W2  = (const float*)d_in[4];
    float* out = (float*)d_out;

    // ws: dnT 16MB @0 (dead after k2b -> region reused as uT 32MB) |
    //     sigT 96MB @32MB | totals 512KB @128MB
    unsigned short* dnT = (unsigned short*)d_ws;
    unsigned short* uT = (unsigned short*)d_ws;
    unsigned short* sigT = (unsigned short*)((char*)d_ws + (size_t)NROWS * NCOH * sizeof(float));
    float* totals = (float*)((char*)d_ws + (size_t)128 * 1024 * 1024);

    k0_w12<<<(2 * NBS * NIN) / 256, 256, 0, stream>>>(W12);
    k0b_w11<<<128, 256, 0, stream>>>(W11);
    k1_fc11<<<NROWS / 128, 256, 0, stream>>>(x, b11, dnT);
    k2a<<<NB * 8, 64, 0, stream>>>(dnT, totals);
    k2b<<<NB * 8, 64, 0, stream>>>(dnT, totals);
    k3_mfma<<<3072, 256, 0, stream>>>(sigT);
    k4_scan<<<NB, 512, 0, stream>>>(sigT, uT);
    k5_out<<<NROWS / 256, 256, 0, stream>>>(sigT, uT, W2, out);
}